// Round 13
// baseline (428.500 us; speedup 1.0000x reference)
//
#include <hip/hip_runtime.h>
#include <math.h>

#define T_LEN 32768
#define NCH   16
#define NB    8
#define NWIN  252
#define NBAND 6
#define NPAIR 136

typedef float v2f __attribute__((ext_vector_type(2)));

// compile-time upper-triangle pair table (p -> (c,d))
struct PairTab { int c[NPAIR]; int d[NPAIR]; };
constexpr PairTab mkpairs() {
    PairTab P{}; int p = 0;
    for (int c = 0; c < 16; ++c)
        for (int d = c; d < 16; ++d) { P.c[p] = c; P.d[p] = d; ++p; }
    return P;
}
constexpr PairTab PT = mkpairs();

// CSD accumulate for wave-group G: pairs {G, G+8, ..., G+128} (17 pairs).
template<int G>
__device__ __forceinline__ void acc_csd(const v2f* __restrict__ X,
                                        v2f* __restrict__ acc)
{
#pragma unroll
    for (int t = 0; t < 17; ++t) {
        const int c = PT.c[G + 8 * t];
        const int d = PT.d[G + 8 * t];
        v2f Xc = X[c], Xd = X[d];
        acc[t] = __builtin_elementwise_fma(Xc, Xd.xx, acc[t]);
        acc[t] = __builtin_elementwise_fma((v2f){Xc.y, -Xc.x}, Xd.yy, acc[t]);
    }
}

// cross-lane exchange helpers (R4/R11-proven set only)
#define SWZ(v, imm)  __int_as_float(__builtin_amdgcn_ds_swizzle(__float_as_int(v), (imm)))
#define DPPQ(v, ctl) __int_as_float(__builtin_amdgcn_mov_dpp(__float_as_int(v), (ctl), 0xF, 0xF, true))

// packed radix-2 DIF butterfly: v = {re, im}; partner p via EX per component.
__device__ __forceinline__ void bfv(v2f& v, v2f p, v2f tw, v2f twn, v2f sg)
{
    v2f t = __builtin_elementwise_fma(sg, v, p);
    v = __builtin_elementwise_fma(t.xx, tw, t.yy * twn);
}
#define BF2(v, EX, TW, TWN, SG) \
    { v2f p_; p_.x = EX(v.x); p_.y = EX(v.y); bfv(v, p_, TW, TWN, SG); }

// ---------------------------------------------------------------------------
// Kernel 1: fused STFT + CSD + band averaging. One 512-thread block per (b,w).
// R11 structure (single-barrier ping-pong) with wave g owning ADJACENT
// channels (2g, 2g+1): the two untangled spectra pack into one float4 ->
// one b128 X2 write and 8 contiguous b128 CSD reads (was 2+16 b64).
// DS ops/wave-frame: 22 -> 12. Exchange network: R4-proven primitives only.
// ---------------------------------------------------------------------------
__global__ __launch_bounds__(512, 2) void csd_band_kernel(const float* __restrict__ x,
                                                          float* __restrict__ band)
{
    const int w    = blockIdx.x;
    const int b    = blockIdx.y;
    const int tid  = threadIdx.x;
    const int lane = tid & 63;
    const int g    = tid >> 6;     // wave id 0..7 -> channels 2g, 2g+1
    const int f    = lane + 1;     // this lane's output bin (1..64)

    __shared__ float4 X2[2][8][64];     // ping-pong packed STFT exchange (16 KB)
    __shared__ v2f    scr[8][64][2];    // per-wave untangle scratch (8 KB)
    __shared__ float  bl[NBAND][NPAIR]; // band |csd|^2 sums
    __shared__ unsigned char pc_[NPAIR], pd_[NPAIR];

    // ---- init ----
    for (int i = tid; i < NBAND * NPAIR; i += 512) (&bl[0][0])[i] = 0.f;
    if (tid < NPAIR) {
        int rem = tid, c = 0;
        while (rem >= 16 - c) { rem -= 16 - c; ++c; }
        pc_[tid] = (unsigned char)c; pd_[tid] = (unsigned char)(c + rem);
    }

    // window (incl. 1/||w||): hanning(128)[n] = .5-.5cos(2*pi*n/127), ||w||^2=47.625
    const double PI = 3.14159265358979323846;
    const float  WI = (float)(1.0 / sqrt(47.625));
    const float wlo = (float)(0.5 - 0.5 * cos(2.0 * PI * (double)lane / 127.0)) * WI;
    const float whi = (float)(0.5 - 0.5 * cos(2.0 * PI * (double)(lane + 64) / 127.0)) * WI;

    // FFT twiddles (per lane, computed once); packed forms TW={r,i}, TWN={-i,r}
    const float PIF = 3.14159265358979f;
    float w128r, w128i;
    { float a = -2.f * PIF * (float)lane / 128.f; sincosf(a, &w128i, &w128r); }
    float t32r, t32i, t16r, t16i, t8r, t8i, t4r, t4i, t2r, t2i;
    { float a = (lane & 32) ? -2.f * PIF * (float)(lane & 31) / 64.f : 0.f; sincosf(a, &t32i, &t32r); }
    { float a = (lane & 16) ? -2.f * PIF * (float)(lane & 15) / 32.f : 0.f; sincosf(a, &t16i, &t16r); }
    { float a = (lane &  8) ? -2.f * PIF * (float)(lane &  7) / 16.f : 0.f; sincosf(a, &t8i,  &t8r ); }
    { float a = (lane &  4) ? -2.f * PIF * (float)(lane &  3) /  8.f : 0.f; sincosf(a, &t4i,  &t4r ); }
    { float a = (lane &  2) ? -2.f * PIF * (float)(lane &  1) /  4.f : 0.f; sincosf(a, &t2i,  &t2r ); }
    const v2f TWH  = { w128r,  w128i }, TWHN = { -w128i, w128r };
    const v2f TW32 = { t32r, t32i },    TW32N = { -t32i, t32r };
    const v2f TW16 = { t16r, t16i },    TW16N = { -t16i, t16r };
    const v2f TW8  = { t8r,  t8i  },    TW8N  = { -t8i,  t8r  };
    const v2f TW4  = { t4r,  t4i  },    TW4N  = { -t4i,  t4r  };
    const v2f TW2  = { t2r,  t2i  },    TW2N  = { -t2i,  t2r  };
    const v2f SG32 = { (lane & 32) ? -1.f : 1.f, (lane & 32) ? -1.f : 1.f };
    const v2f SG16 = { (lane & 16) ? -1.f : 1.f, (lane & 16) ? -1.f : 1.f };
    const v2f SG8  = { (lane &  8) ? -1.f : 1.f, (lane &  8) ? -1.f : 1.f };
    const v2f SG4  = { (lane &  4) ? -1.f : 1.f, (lane &  4) ? -1.f : 1.f };
    const v2f SG2  = { (lane &  2) ? -1.f : 1.f, (lane &  2) ? -1.f : 1.f };
    const v2f SG1  = { (lane &  1) ? -1.f : 1.f, (lane &  1) ? -1.f : 1.f };

    const int bp32 = 4 * (lane ^ 32);
    // untangle gather: U[k] lives at slot k&1, lane bitrev6(k>>1)
    const int La = (int)(__brev((unsigned)(f >> 1)) >> 26);
    const int Lb = (int)(__brev((unsigned)((128 - f) >> 1)) >> 26);
    const int pa = f & 1;

    v2f acc[17];
#pragma unroll
    for (int t = 0; t < 17; ++t) acc[t] = (v2f){0.f, 0.f};

    // wave g owns adjacent channels 2g (real-pack) and 2g+1 (imag-pack)
    const float* xp0 = x + (size_t)(b * NCH + 2 * g) * T_LEN + (size_t)w * 128;
    const float* xp1 = xp0 + (size_t)T_LEN;

    __syncthreads();

    for (int s = 0; s < 16; ++s) {
        // ---- load + window + pack: u = xw_{2g} + i*xw_{2g+1}
        v2f S0 = (v2f){ xp0[s * 32 + lane],      xp1[s * 32 + lane]      } * wlo;
        v2f S1 = (v2f){ xp0[s * 32 + lane + 64], xp1[s * 32 + lane + 64] } * whi;

        // ---- stage span=64 (in-lane): S0=a+b, S1=(a-b)*W128^lane
        {
            v2f D = S0 - S1;
            S0 = S0 + S1;
            S1 = __builtin_elementwise_fma(D.xx, TWH, D.yy * TWHN);
        }
#define EX32(v) __int_as_float(__builtin_amdgcn_ds_bpermute(bp32, __float_as_int(v)))
#define EX16(v) SWZ(v, 0x401F)
#define EX8(v)  DPPQ(v, 0x128)   // row_ror:8 == lane^8 (R9/R10-verified)
#define EX4(v)  SWZ(v, 0x101F)
#define EX2(v)  DPPQ(v, 0x4E)    // quad_perm [2,3,0,1] = xor2
#define EX1(v)  DPPQ(v, 0xB1)    // quad_perm [1,0,3,2] = xor1
        BF2(S0, EX32, TW32, TW32N, SG32)
        BF2(S1, EX32, TW32, TW32N, SG32)
        BF2(S0, EX16, TW16, TW16N, SG16)
        BF2(S1, EX16, TW16, TW16N, SG16)
        BF2(S0, EX8,  TW8,  TW8N,  SG8)
        BF2(S1, EX8,  TW8,  TW8N,  SG8)
        BF2(S0, EX4,  TW4,  TW4N,  SG4)
        BF2(S1, EX4,  TW4,  TW4N,  SG4)
        BF2(S0, EX2,  TW2,  TW2N,  SG2)
        BF2(S1, EX2,  TW2,  TW2N,  SG2)
        {   // last stage span=1: no twiddle
            v2f p_; p_.x = EX1(S0.x); p_.y = EX1(S0.y);
            S0 = __builtin_elementwise_fma(SG1, S0, p_);
        }
        {
            v2f p_; p_.x = EX1(S1.x); p_.y = EX1(S1.y);
            S1 = __builtin_elementwise_fma(SG1, S1, p_);
        }

        // ---- untangle via per-wave scratch (wave-synchronous)
        // contiguous 16B per lane -> compiler merges into one ds_write_b128
        scr[g][lane][0] = S0;
        scr[g][lane][1] = S1;
        v2f Ua = scr[g][La][pa];   // U[f]
        v2f Ub = scr[g][Lb][pa];   // U[128-f]
        v2f X0 = { 0.5f * (Ua.x + Ub.x), 0.5f * (Ua.y - Ub.y) };  // ch 2g
        v2f X1 = { 0.5f * (Ua.y + Ub.y), 0.5f * (Ub.x - Ua.x) };  // ch 2g+1

        // ---- ping-pong exchange: ONE b128 write, single barrier (R11-proven)
        const int pp = s & 1;
        X2[pp][g][lane] = make_float4(X0.x, X0.y, X1.x, X1.y);
        __syncthreads();

        // ---- CSD accumulate: 8 contiguous b128 reads for all 16 channels
        v2f X[16];
#pragma unroll
        for (int c = 0; c < 8; ++c) {
            float4 v = X2[pp][c][lane];
            X[2 * c]     = (v2f){ v.x, v.y };
            X[2 * c + 1] = (v2f){ v.z, v.w };
        }
        switch (g) {
            case 0: acc_csd<0>(X, acc); break;
            case 1: acc_csd<1>(X, acc); break;
            case 2: acc_csd<2>(X, acc); break;
            case 3: acc_csd<3>(X, acc); break;
            case 4: acc_csd<4>(X, acc); break;
            case 5: acc_csd<5>(X, acc); break;
            case 6: acc_csd<6>(X, acc); break;
            default: acc_csd<7>(X, acc); break;
        }
    }

    // ---- band reduction ----
    const int kband = (lane < 6) ? 0 : (lane < 12) ? 1 : (lane < 19) ? 2
                    : (lane < 32) ? 3 : (lane < 48) ? 4 : 5;
#pragma unroll
    for (int t = 0; t < 17; ++t) {
        float vv = fmaf(acc[t].x, acc[t].x, acc[t].y * acc[t].y);
        atomicAdd(&bl[kband][g + 8 * t], vv);
    }
    __syncthreads();

    const float rs[NBAND] = { 1.f/(256.f*6.f), 1.f/(256.f*6.f), 1.f/(256.f*7.f),
                              1.f/(256.f*13.f), 1.f/(256.f*16.f), 1.f/(256.f*16.f) };
    float* bb = band + (size_t)(b * NWIN + w) * (NBAND * 256);
    for (int i = tid; i < NBAND * NPAIR; i += 512) {
        int k = i / NPAIR, p = i - k * NPAIR;
        int c = pc_[p], d = pd_[p];
        float val = bl[k][p] * rs[k];
        bb[k * 256 + c * 16 + d] = val;
        bb[k * 256 + d * 16 + c] = val;
    }
}

// ---------------------------------------------------------------------------
// Kernel 2: 16x16 symmetric eigendecomposition, fp32 parallel Jacobi
// (tournament ordering, 4 sweeps). 8 matrices per 512-thread block, ONE WAVE
// per matrix, fully wave-synchronous: zero barriers.  [R5/R7/R10/R11-proven]
// ---------------------------------------------------------------------------
__device__ __forceinline__ void tourney(int rr, int j, int& p, int& q)
{
    if (j == 0) { p = 15; q = rr; }
    else { p = (rr + j) % 15; q = (rr + 15 - j) % 15; }
    if (p > q) { int t_ = p; p = q; q = t_; }
}

__global__ __launch_bounds__(512) void eig_log_kernel(const float* __restrict__ band,
                                                      float* __restrict__ out)
{
    const int tid  = threadIdx.x;
    const int g    = tid >> 6;          // matrix slot in block (one wave each)
    const int lane = tid & 63;
    const int m    = blockIdx.x * 8 + g;           // 0..12095
    const int k    = m % NBAND;
    const int bw   = m / NBAND;
    const int w    = bw % NWIN;
    const int b    = bw / NWIN;
    const int j    = lane >> 3;   // pair 0..7
    const int n2   = lane & 7;    // column-pair 0..7

    __shared__ float A[8][16][18];
    __shared__ float DT[8][16][18];
    __shared__ float VT[8][16][18];
    __shared__ float lv[8][16];

    const float* M = band + ((size_t)(b * NWIN + w) * NBAND + k) * 256;
#pragma unroll
    for (int it = 0; it < 4; ++it) {
        int i = lane + it * 64, r = i >> 4, c = i & 15;
        A[g][r][c]  = M[i];
        VT[g][r][c] = (r == c) ? 1.f : 0.f;
    }
    // wave-synchronous from here on: no __syncthreads anywhere

    for (int sweep = 0; sweep < 4; ++sweep) {
        for (int rr = 0; rr < 15; ++rr) {
            int p, q; tourney(rr, j, p, q);
            // phase A: rotation params + DT = A*J (stored transposed)
            float app = A[g][p][p], aqq = A[g][q][q], apq = A[g][p][q];
            float c_ = 1.f, s_ = 0.f;
            if (apq != 0.f) {
                float tau = (aqq - app) / (2.f * apq);
                float t   = copysignf(1.f, tau) / (fabsf(tau) + sqrtf(1.f + tau * tau));
                c_ = 1.f / sqrtf(1.f + t * t);
                s_ = t * c_;
            }
            float2 ap = *(const float2*)&A[g][p][2 * n2];
            float2 aq = *(const float2*)&A[g][q][2 * n2];
            DT[g][2 * n2][p]     = c_ * ap.x - s_ * aq.x;
            DT[g][2 * n2 + 1][p] = c_ * ap.y - s_ * aq.y;
            DT[g][2 * n2][q]     = s_ * ap.x + c_ * aq.x;
            DT[g][2 * n2 + 1][q] = s_ * ap.y + c_ * aq.y;

            // phase B: A' = J^T * DT ; VT' = J^T * VT  (c_,s_ reused from regs)
            float2 dp = *(const float2*)&DT[g][p][2 * n2];
            float2 dq = *(const float2*)&DT[g][q][2 * n2];
            *(float2*)&A[g][p][2 * n2] = make_float2(c_ * dp.x - s_ * dq.x,
                                                     c_ * dp.y - s_ * dq.y);
            *(float2*)&A[g][q][2 * n2] = make_float2(s_ * dp.x + c_ * dq.x,
                                                     s_ * dp.y + c_ * dq.y);
            float2 vp = *(const float2*)&VT[g][p][2 * n2];
            float2 vq = *(const float2*)&VT[g][q][2 * n2];
            *(float2*)&VT[g][p][2 * n2] = make_float2(c_ * vp.x - s_ * vq.x,
                                                      c_ * vp.y - s_ * vq.y);
            *(float2*)&VT[g][q][2 * n2] = make_float2(s_ * vp.x + c_ * vq.x,
                                                      s_ * vp.y + c_ * vq.y);
        }
    }

    if (lane < 16) {
        float l = logf(A[g][lane][lane]);
        if (isnan(l) || isinf(l)) l = 0.f;   // nan_to_num(nan=0, neginf=0)
        lv[g][lane] = l;
    }

    // out[b][k][c][d][w] = sum_e VT[e][c] * lv[e] * VT[e][d]
    float* ob = out + (size_t)(b * NBAND + k) * 256 * NWIN;
#pragma unroll
    for (int it = 0; it < 4; ++it) {
        int i = lane + it * 64, c = i >> 4, d = i & 15;
        float sum = 0.f;
#pragma unroll
        for (int e = 0; e < 16; ++e) sum = fmaf(VT[g][e][c] * lv[g][e], VT[g][e][d], sum);
        ob[(size_t)i * NWIN + w] = sum;
    }
}

// ---------------------------------------------------------------------------
extern "C" void kernel_launch(void* const* d_in, const int* in_sizes, int n_in,
                              void* d_out, int out_size, void* d_ws, size_t ws_size,
                              hipStream_t stream)
{
    const float* x    = (const float*)d_in[0];
    float*       out  = (float*)d_out;
    float*       band = (float*)d_ws;   // 8*252*6*256*4 = 12,386,304 bytes

    dim3 g1(NWIN, NB), b1(512);
    hipLaunchKernelGGL(csd_band_kernel, g1, b1, 0, stream, x, band);

    dim3 g2(NB * NWIN * NBAND / 8), b2(512);
    hipLaunchKernelGGL(eig_log_kernel, g2, b2, 0, stream, band, out);
}

// Round 14
// 355.590 us; speedup vs baseline: 1.2050x; 1.2050x over previous
//
#include <hip/hip_runtime.h>
#include <math.h>

#define T_LEN 32768
#define NCH   16
#define NB    8
#define NWIN  252
#define NBAND 6
#define NPAIR 136

typedef float v2f __attribute__((ext_vector_type(2)));

// compile-time upper-triangle pair table (p -> (c,d))
struct PairTab { int c[NPAIR]; int d[NPAIR]; };
constexpr PairTab mkpairs() {
    PairTab P{}; int p = 0;
    for (int c = 0; c < 16; ++c)
        for (int d = c; d < 16; ++d) { P.c[p] = c; P.d[p] = d; ++p; }
    return P;
}
constexpr PairTab PT = mkpairs();

// CSD accumulate for wave-group G: pairs {G, G+8, ..., G+128} (17 pairs).
template<int G>
__device__ __forceinline__ void acc_csd(const v2f* __restrict__ X,
                                        v2f* __restrict__ acc)
{
#pragma unroll
    for (int t = 0; t < 17; ++t) {
        const int c = PT.c[G + 8 * t];
        const int d = PT.d[G + 8 * t];
        v2f Xc = X[c], Xd = X[d];
        acc[t] = __builtin_elementwise_fma(Xc, Xd.xx, acc[t]);
        acc[t] = __builtin_elementwise_fma((v2f){Xc.y, -Xc.x}, Xd.yy, acc[t]);
    }
}

// cross-lane exchange helpers (R4/R11-proven set only)
#define SWZ(v, imm)  __int_as_float(__builtin_amdgcn_ds_swizzle(__float_as_int(v), (imm)))
#define DPPQ(v, ctl) __int_as_float(__builtin_amdgcn_mov_dpp(__float_as_int(v), (ctl), 0xF, 0xF, true))

// packed radix-2 DIF butterfly: v = {re, im}; partner p via EX per component.
__device__ __forceinline__ void bfv(v2f& v, v2f p, v2f tw, v2f twn, v2f sg)
{
    v2f t = __builtin_elementwise_fma(sg, v, p);
    v = __builtin_elementwise_fma(t.xx, tw, t.yy * twn);
}
#define BF2(v, EX, TW, TWN, SG) \
    { v2f p_; p_.x = EX(v.x); p_.y = EX(v.y); bfv(v, p_, TW, TWN, SG); }

// ---------------------------------------------------------------------------
// Kernel 1: fused STFT + CSD + band averaging. One 512-thread block per (b,w).
// R11 structure (single-barrier ping-pong, VGPR=64). scr uses a diagonal-pad
// layout [2][4][17] so the bit-reversed untangle gathers hit distinct banks
// (was 4-way conflicted: bank = 2*(La mod 16), La repeats mod 16 4x/wave).
// ---------------------------------------------------------------------------
__global__ __launch_bounds__(512, 2) void csd_band_kernel(const float* __restrict__ x,
                                                          float* __restrict__ band)
{
    const int w    = blockIdx.x;
    const int b    = blockIdx.y;
    const int tid  = threadIdx.x;
    const int lane = tid & 63;
    const int g    = tid >> 6;     // wave id 0..7
    const int f    = lane + 1;     // this lane's output bin (1..64)

    __shared__ v2f  X2[2][NCH][64];     // ping-pong STFT exchange (16 KB)
    __shared__ v2f  scr[8][2][4][17];   // diag-padded untangle scratch (8.5 KB)
    __shared__ float bl[NBAND][NPAIR];  // band |csd|^2 sums
    __shared__ unsigned char pc_[NPAIR], pd_[NPAIR];

    // ---- init ----
    for (int i = tid; i < NBAND * NPAIR; i += 512) (&bl[0][0])[i] = 0.f;
    if (tid < NPAIR) {
        int rem = tid, c = 0;
        while (rem >= 16 - c) { rem -= 16 - c; ++c; }
        pc_[tid] = (unsigned char)c; pd_[tid] = (unsigned char)(c + rem);
    }

    // window (incl. 1/||w||): hanning(128)[n] = .5-.5cos(2*pi*n/127), ||w||^2=47.625
    const double PI = 3.14159265358979323846;
    const float  WI = (float)(1.0 / sqrt(47.625));
    const float wlo = (float)(0.5 - 0.5 * cos(2.0 * PI * (double)lane / 127.0)) * WI;
    const float whi = (float)(0.5 - 0.5 * cos(2.0 * PI * (double)(lane + 64) / 127.0)) * WI;

    // FFT twiddles (per lane, computed once); packed forms TW={r,i}, TWN={-i,r}
    const float PIF = 3.14159265358979f;
    float w128r, w128i;
    { float a = -2.f * PIF * (float)lane / 128.f; sincosf(a, &w128i, &w128r); }
    float t32r, t32i, t16r, t16i, t8r, t8i, t4r, t4i, t2r, t2i;
    { float a = (lane & 32) ? -2.f * PIF * (float)(lane & 31) / 64.f : 0.f; sincosf(a, &t32i, &t32r); }
    { float a = (lane & 16) ? -2.f * PIF * (float)(lane & 15) / 32.f : 0.f; sincosf(a, &t16i, &t16r); }
    { float a = (lane &  8) ? -2.f * PIF * (float)(lane &  7) / 16.f : 0.f; sincosf(a, &t8i,  &t8r ); }
    { float a = (lane &  4) ? -2.f * PIF * (float)(lane &  3) /  8.f : 0.f; sincosf(a, &t4i,  &t4r ); }
    { float a = (lane &  2) ? -2.f * PIF * (float)(lane &  1) /  4.f : 0.f; sincosf(a, &t2i,  &t2r ); }
    const v2f TWH  = { w128r,  w128i }, TWHN = { -w128i, w128r };
    const v2f TW32 = { t32r, t32i },    TW32N = { -t32i, t32r };
    const v2f TW16 = { t16r, t16i },    TW16N = { -t16i, t16r };
    const v2f TW8  = { t8r,  t8i  },    TW8N  = { -t8i,  t8r  };
    const v2f TW4  = { t4r,  t4i  },    TW4N  = { -t4i,  t4r  };
    const v2f TW2  = { t2r,  t2i  },    TW2N  = { -t2i,  t2r  };
    const v2f SG32 = { (lane & 32) ? -1.f : 1.f, (lane & 32) ? -1.f : 1.f };
    const v2f SG16 = { (lane & 16) ? -1.f : 1.f, (lane & 16) ? -1.f : 1.f };
    const v2f SG8  = { (lane &  8) ? -1.f : 1.f, (lane &  8) ? -1.f : 1.f };
    const v2f SG4  = { (lane &  4) ? -1.f : 1.f, (lane &  4) ? -1.f : 1.f };
    const v2f SG2  = { (lane &  2) ? -1.f : 1.f, (lane &  2) ? -1.f : 1.f };
    const v2f SG1  = { (lane &  1) ? -1.f : 1.f, (lane &  1) ? -1.f : 1.f };

    const int bp32 = 4 * (lane ^ 32);
    // untangle gather: U[k] lives at slot k&1, lane bitrev6(k>>1)
    const int La = (int)(__brev((unsigned)(f >> 1)) >> 26);
    const int Lb = (int)(__brev((unsigned)((128 - f) >> 1)) >> 26);
    const int pa = f & 1;

    v2f acc[17];
#pragma unroll
    for (int t = 0; t < 17; ++t) acc[t] = (v2f){0.f, 0.f};

    const float* xp0 = x + (size_t)(b * NCH + g) * T_LEN + (size_t)w * 128;
    const float* xp1 = xp0 + 8 * (size_t)T_LEN;

    __syncthreads();

    for (int s = 0; s < 16; ++s) {
        // ---- load + window + pack: u = xw_g + i*xw_{g+8}
        v2f S0 = (v2f){ xp0[s * 32 + lane],      xp1[s * 32 + lane]      } * wlo;
        v2f S1 = (v2f){ xp0[s * 32 + lane + 64], xp1[s * 32 + lane + 64] } * whi;

        // ---- stage span=64 (in-lane): S0=a+b, S1=(a-b)*W128^lane
        {
            v2f D = S0 - S1;
            S0 = S0 + S1;
            S1 = __builtin_elementwise_fma(D.xx, TWH, D.yy * TWHN);
        }
#define EX32(v) __int_as_float(__builtin_amdgcn_ds_bpermute(bp32, __float_as_int(v)))
#define EX16(v) SWZ(v, 0x401F)
#define EX8(v)  DPPQ(v, 0x128)   // row_ror:8 == lane^8 (R9/R10/R11-verified)
#define EX4(v)  SWZ(v, 0x101F)
#define EX2(v)  DPPQ(v, 0x4E)    // quad_perm [2,3,0,1] = xor2
#define EX1(v)  DPPQ(v, 0xB1)    // quad_perm [1,0,3,2] = xor1
        BF2(S0, EX32, TW32, TW32N, SG32)
        BF2(S1, EX32, TW32, TW32N, SG32)
        BF2(S0, EX16, TW16, TW16N, SG16)
        BF2(S1, EX16, TW16, TW16N, SG16)
        BF2(S0, EX8,  TW8,  TW8N,  SG8)
        BF2(S1, EX8,  TW8,  TW8N,  SG8)
        BF2(S0, EX4,  TW4,  TW4N,  SG4)
        BF2(S1, EX4,  TW4,  TW4N,  SG4)
        BF2(S0, EX2,  TW2,  TW2N,  SG2)
        BF2(S1, EX2,  TW2,  TW2N,  SG2)
        {   // last stage span=1: no twiddle
            v2f p_; p_.x = EX1(S0.x); p_.y = EX1(S0.y);
            S0 = __builtin_elementwise_fma(SG1, S0, p_);
        }
        {
            v2f p_; p_.x = EX1(S1.x); p_.y = EX1(S1.y);
            S1 = __builtin_elementwise_fma(SG1, S1, p_);
        }

        // ---- untangle via diag-padded per-wave scratch (wave-synchronous)
        scr[g][0][lane >> 4][lane & 15] = S0;
        scr[g][1][lane >> 4][lane & 15] = S1;
        v2f Ua = scr[g][pa][La >> 4][La & 15];   // U[f]
        v2f Ub = scr[g][pa][Lb >> 4][Lb & 15];   // U[128-f]
        v2f X0 = { 0.5f * (Ua.x + Ub.x), 0.5f * (Ua.y - Ub.y) };
        v2f X1 = { 0.5f * (Ua.y + Ub.y), 0.5f * (Ub.x - Ua.x) };

        // ---- ping-pong exchange: single barrier per frame (R11-proven)
        const int pp = s & 1;
        X2[pp][g][lane]     = X0;
        X2[pp][g + 8][lane] = X1;
        __syncthreads();

        // ---- CSD accumulate (packed registers) ----
        v2f X[16];
#pragma unroll
        for (int c = 0; c < 16; ++c) X[c] = X2[pp][c][lane];
        switch (g) {
            case 0: acc_csd<0>(X, acc); break;
            case 1: acc_csd<1>(X, acc); break;
            case 2: acc_csd<2>(X, acc); break;
            case 3: acc_csd<3>(X, acc); break;
            case 4: acc_csd<4>(X, acc); break;
            case 5: acc_csd<5>(X, acc); break;
            case 6: acc_csd<6>(X, acc); break;
            default: acc_csd<7>(X, acc); break;
        }
    }

    // ---- band reduction ----
    const int kband = (lane < 6) ? 0 : (lane < 12) ? 1 : (lane < 19) ? 2
                    : (lane < 32) ? 3 : (lane < 48) ? 4 : 5;
#pragma unroll
    for (int t = 0; t < 17; ++t) {
        float vv = fmaf(acc[t].x, acc[t].x, acc[t].y * acc[t].y);
        atomicAdd(&bl[kband][g + 8 * t], vv);
    }
    __syncthreads();

    const float rs[NBAND] = { 1.f/(256.f*6.f), 1.f/(256.f*6.f), 1.f/(256.f*7.f),
                              1.f/(256.f*13.f), 1.f/(256.f*16.f), 1.f/(256.f*16.f) };
    float* bb = band + (size_t)(b * NWIN + w) * (NBAND * 256);
    for (int i = tid; i < NBAND * NPAIR; i += 512) {
        int k = i / NPAIR, p = i - k * NPAIR;
        int c = pc_[p], d = pd_[p];
        float val = bl[k][p] * rs[k];
        bb[k * 256 + c * 16 + d] = val;
        bb[k * 256 + d * 16 + c] = val;
    }
}

// ---------------------------------------------------------------------------
// Kernel 2: 16x16 symmetric eigendecomposition, fp32 parallel Jacobi
// (tournament ordering, 4 sweeps). 8 matrices per 512-thread block, ONE WAVE
// per matrix, fully wave-synchronous: zero barriers.  [R5/R7/R10/R11-proven]
// ---------------------------------------------------------------------------
__device__ __forceinline__ void tourney(int rr, int j, int& p, int& q)
{
    if (j == 0) { p = 15; q = rr; }
    else { p = (rr + j) % 15; q = (rr + 15 - j) % 15; }
    if (p > q) { int t_ = p; p = q; q = t_; }
}

__global__ __launch_bounds__(512) void eig_log_kernel(const float* __restrict__ band,
                                                      float* __restrict__ out)
{
    const int tid  = threadIdx.x;
    const int g    = tid >> 6;          // matrix slot in block (one wave each)
    const int lane = tid & 63;
    const int m    = blockIdx.x * 8 + g;           // 0..12095
    const int k    = m % NBAND;
    const int bw   = m / NBAND;
    const int w    = bw % NWIN;
    const int b    = bw / NWIN;
    const int j    = lane >> 3;   // pair 0..7
    const int n2   = lane & 7;    // column-pair 0..7

    __shared__ float A[8][16][18];
    __shared__ float DT[8][16][18];
    __shared__ float VT[8][16][18];
    __shared__ float lv[8][16];

    const float* M = band + ((size_t)(b * NWIN + w) * NBAND + k) * 256;
#pragma unroll
    for (int it = 0; it < 4; ++it) {
        int i = lane + it * 64, r = i >> 4, c = i & 15;
        A[g][r][c]  = M[i];
        VT[g][r][c] = (r == c) ? 1.f : 0.f;
    }
    // wave-synchronous from here on: no __syncthreads anywhere

    for (int sweep = 0; sweep < 4; ++sweep) {
        for (int rr = 0; rr < 15; ++rr) {
            int p, q; tourney(rr, j, p, q);
            // phase A: rotation params + DT = A*J (stored transposed)
            float app = A[g][p][p], aqq = A[g][q][q], apq = A[g][p][q];
            float c_ = 1.f, s_ = 0.f;
            if (apq != 0.f) {
                float tau = (aqq - app) / (2.f * apq);
                float t   = copysignf(1.f, tau) / (fabsf(tau) + sqrtf(1.f + tau * tau));
                c_ = 1.f / sqrtf(1.f + t * t);
                s_ = t * c_;
            }
            float2 ap = *(const float2*)&A[g][p][2 * n2];
            float2 aq = *(const float2*)&A[g][q][2 * n2];
            DT[g][2 * n2][p]     = c_ * ap.x - s_ * aq.x;
            DT[g][2 * n2 + 1][p] = c_ * ap.y - s_ * aq.y;
            DT[g][2 * n2][q]     = s_ * ap.x + c_ * aq.x;
            DT[g][2 * n2 + 1][q] = s_ * ap.y + c_ * aq.y;

            // phase B: A' = J^T * DT ; VT' = J^T * VT  (c_,s_ reused from regs)
            float2 dp = *(const float2*)&DT[g][p][2 * n2];
            float2 dq = *(const float2*)&DT[g][q][2 * n2];
            *(float2*)&A[g][p][2 * n2] = make_float2(c_ * dp.x - s_ * dq.x,
                                                     c_ * dp.y - s_ * dq.y);
            *(float2*)&A[g][q][2 * n2] = make_float2(s_ * dp.x + c_ * dq.x,
                                                     s_ * dp.y + c_ * dq.y);
            float2 vp = *(const float2*)&VT[g][p][2 * n2];
            float2 vq = *(const float2*)&VT[g][q][2 * n2];
            *(float2*)&VT[g][p][2 * n2] = make_float2(c_ * vp.x - s_ * vq.x,
                                                      c_ * vp.y - s_ * vq.y);
            *(float2*)&VT[g][q][2 * n2] = make_float2(s_ * vp.x + c_ * vq.x,
                                                      s_ * vp.y + c_ * vq.y);
        }
    }

    if (lane < 16) {
        float l = logf(A[g][lane][lane]);
        if (isnan(l) || isinf(l)) l = 0.f;   // nan_to_num(nan=0, neginf=0)
        lv[g][lane] = l;
    }

    // out[b][k][c][d][w] = sum_e VT[e][c] * lv[e] * VT[e][d]
    float* ob = out + (size_t)(b * NBAND + k) * 256 * NWIN;
#pragma unroll
    for (int it = 0; it < 4; ++it) {
        int i = lane + it * 64, c = i >> 4, d = i & 15;
        float sum = 0.f;
#pragma unroll
        for (int e = 0; e < 16; ++e) sum = fmaf(VT[g][e][c] * lv[g][e], VT[g][e][d], sum);
        ob[(size_t)i * NWIN + w] = sum;
    }
}

// ---------------------------------------------------------------------------
extern "C" void kernel_launch(void* const* d_in, const int* in_sizes, int n_in,
                              void* d_out, int out_size, void* d_ws, size_t ws_size,
                              hipStream_t stream)
{
    const float* x    = (const float*)d_in[0];
    float*       out  = (float*)d_out;
    float*       band = (float*)d_ws;   // 8*252*6*256*4 = 12,386,304 bytes

    dim3 g1(NWIN, NB), b1(512);
    hipLaunchKernelGGL(csd_band_kernel, g1, b1, 0, stream, x, band);

    dim3 g2(NB * NWIN * NBAND / 8), b2(512);
    hipLaunchKernelGGL(eig_log_kernel, g2, b2, 0, stream, band, out);
}